// Round 3
// baseline (3281.543 us; speedup 1.0000x reference)
//
#include <hip/hip_runtime.h>
#include <hip/hip_bf16.h>
#include <stdint.h>

#define SUBU 20
#define E_NO 2000
#define I_NO 500
#define T_DATA 20000
#define T_SYNK 200
#define T_HISTK 50
#define SBAS 3
#define HBAS 3
#define TPAD 20096          // 1256 * 16

// workspace float offsets
#define OFF_SYN  0          // [20][TPAD]  c[s][t] = syn + theta
#define OFF_INE  401920     // [20][TPAD]
#define OFF_INI  803840     // [20][TPAD]  (reused as Y f32 when bf16 out)
#define OFF_KE   1205760    // [20][200]
#define OFF_KI   1209760    // [20][200]
#define OFF_IIR  1213760    // [20][16] folded IIR consts
#define OFF_MD   1214760    // [20][20] dense M
#define OFF_PAR  1215240    // theta[20], wsub0, vo
#define OFF_FLAG 1215264    // int bf16 flag
#define OFF_Y    OFF_INI

__device__ __forceinline__ float bf2f(unsigned short u){
  unsigned v = ((unsigned)u) << 16; float f; __builtin_memcpy(&f, &v, 4); return f;
}
__device__ __forceinline__ float ldany(const void* p, int i, int bf){
  return bf ? bf2f(((const unsigned short*)p)[i]) : ((const float*)p)[i];
}

// ---------------- dtype detection: S_e is exactly {0,1} -------------------
__global__ __launch_bounds__(256) void k_detect(const void* s_e, int* flag){
  __shared__ int found;
  if (threadIdx.x == 0) found = 0;
  __syncthreads();
  const unsigned* w = (const unsigned*)s_e;
  int hit = 0;
  for (int i = threadIdx.x; i < 8192; i += 256){
    unsigned x = w[i];
    if (x == 0x00003F80u || x == 0x3F803F80u) hit = 1;   // bf16 1.0 patterns
  }
  if (hit) atomicOr(&found, 1);
  __syncthreads();
  if (threadIdx.x == 0) *flag = found;
}

// ---------------- precompute: syn kernels, folded IIR, dense M, params ----
__global__ __launch_bounds__(512) void k_prep(
    const void* Cden, const void* Wsyn, const void* Tausyn, const void* Dsyn,
    const void* Whist, const void* Tauhist, const void* Dhist,
    const void* Wsub, const void* Vo, const void* Theta, float* ws){
  int* wsi = (int*)ws;
  const int bf = wsi[OFF_FLAG];
  const int tx = threadIdx.x;
  // synaptic kernels ke/ki [20][200]
  for (int idx = tx; idx < SUBU * T_SYNK; idx += 512){
    int s = idx / T_SYNK, t = idx % T_SYNK;
    for (int c = 0; c < 2; ++c){
      float delta = __expf(ldany(Dsyn, s*2 + c, bf));
      float acc = 0.f;
      for (int b = 0; b < SBAS; ++b){
        float tau = __expf(ldany(Tausyn, b*2 + c, bf));
        float w   = ldany(Wsyn, (s*SBAS + b)*2 + c, bf);
        float tt  = fmaxf((float)t - delta, 0.f) / tau;
        acc += w * tt * __expf(-tt);
      }
      ws[(c == 0 ? OFF_KE : OFF_KI) + s*T_SYNK + t] = acc;
    }
  }
  // folded per-lane IIR constants (A carries basis weight w)
  if (tx < SUBU * HBAS){
    int s = tx / HBAS, b = tx % HBAS;
    float tau = __expf(ldany(Tauhist, b, bf));
    float w   = ldany(Whist, s*HBAS + b, bf);
    float dl  = ldany(Dhist, s, bf);
    float rho = __expf(-1.f / tau);
    float e1  = __expf(-(1.f - dl) / tau);
    float g1  = ((1.f - dl) / tau) * e1;
    float kap = rho / tau;
    float* c = ws + OFF_IIR + s*16 + b*4;
    c[0] = rho;          // decay
    c[1] = w * kap;      // E -> A
    c[2] = w * g1;       // y_new into A
    c[3] = e1;           // y_new into E
    if (b == 2){         // only the slow basis needs window-correction taps
      float e49 = __expf(-(49.f - dl) / tau);
      float g49 = ((49.f - dl) / tau) * e49;
      ws[OFF_IIR + s*16 + 12] = w * (rho*g49 + kap*e49);  // y_old out of A
      ws[OFF_IIR + s*16 + 13] = rho * e49;                // y_old out of E
    }
  }
  // dense M[s][s'] = C_den[s][s'] * W_sub[s']
  if (tx < SUBU * SUBU){
    int s = tx / SUBU, sp = tx % SUBU;
    ws[OFF_MD + s*SUBU + sp] = ldany(Cden, s*SUBU + sp, bf) * ldany(Wsub, sp, bf);
  }
  if (tx < SUBU) ws[OFF_PAR + tx] = ldany(Theta, tx, bf);
  if (tx == 0){
    ws[OFF_PAR + SUBU]     = ldany(Wsub, 0, bf);
    ws[OFF_PAR + SUBU + 1] = ldany(Vo, 0, bf);
  }
}

// ---------------- skinny GEMM: in_T[s][t] = sum_e S[t][e]*C[s][e] ---------
template<int BF>
__device__ __forceinline__ void gemm_impl(const void* S, const void* C, int W,
                                          float* dst, int t0, int lane){
  float acc[4][SUBU];
  #pragma unroll
  for (int r = 0; r < 4; ++r)
    #pragma unroll
    for (int s = 0; s < SUBU; ++s) acc[r][s] = 0.f;
  for (int e = lane; e < W; e += 64){
    float s0 = ldany(S, (t0+0)*W + e, BF);
    float s1 = ldany(S, (t0+1)*W + e, BF);
    float s2 = ldany(S, (t0+2)*W + e, BF);
    float s3 = ldany(S, (t0+3)*W + e, BF);
    #pragma unroll
    for (int s = 0; s < SUBU; ++s){
      float c = ldany(C, s*W + e, BF);
      acc[0][s] = fmaf(s0, c, acc[0][s]);
      acc[1][s] = fmaf(s1, c, acc[1][s]);
      acc[2][s] = fmaf(s2, c, acc[2][s]);
      acc[3][s] = fmaf(s3, c, acc[3][s]);
    }
  }
  #pragma unroll
  for (int r = 0; r < 4; ++r){
    #pragma unroll
    for (int s = 0; s < SUBU; ++s){
      float v = acc[r][s];
      #pragma unroll
      for (int m = 32; m >= 1; m >>= 1) v += __shfl_xor(v, m, 64);
      if (lane == 0) dst[s*TPAD + t0 + r] = v;
    }
  }
}

__global__ __launch_bounds__(64) void k_gemm(const void* S, const void* C, int W,
                                             float* dst, const int* flagp){
  int t0 = blockIdx.x * 4, lane = threadIdx.x;
  if (*flagp) gemm_impl<1>(S, C, W, dst, t0, lane);
  else        gemm_impl<0>(S, C, W, dst, t0, lane);
}

// ---------------- causal conv (+theta fold): c[s][t] ----------------------
__global__ __launch_bounds__(256) void k_conv(float* ws){
  const int s  = blockIdx.y;
  const int t0 = blockIdx.x * 256;
  const float* ine = ws + OFF_INE + s*TPAD;
  const float* ini = ws + OFF_INI + s*TPAD;
  __shared__ float eL[455], iL[455], keL[T_SYNK], kiL[T_SYNK];
  for (int j = threadIdx.x; j < 455; j += 256){
    int t = t0 - 199 + j;
    bool ok = (t >= 0 && t < TPAD);
    eL[j] = ok ? ine[t] : 0.f;
    iL[j] = ok ? ini[t] : 0.f;
  }
  for (int j = threadIdx.x; j < T_SYNK; j += 256){
    keL[j] = ws[OFF_KE + s*T_SYNK + j];
    kiL[j] = ws[OFF_KI + s*T_SYNK + j];
  }
  __syncthreads();
  int t = t0 + threadIdx.x;
  if (t < TPAD){
    float a0 = 0.f, a1 = 0.f;
    #pragma unroll 4
    for (int k = 0; k < T_SYNK; ++k){
      a0 = fmaf(keL[k], eL[threadIdx.x + 199 - k], a0);
      a1 = fmaf(kiL[k], iL[threadIdx.x + 199 - k], a1);
    }
    ws[OFF_SYN + s*TPAD + t] = a0 + a1 + ws[OFF_PAR + s];
  }
}

// ---------------- static float4 component helpers (fold under unroll) -----
__device__ __forceinline__ float get4(const float4& a, const float4& b,
                                      const float4& c, const float4& d, int u){
  const float4& q = (u < 4) ? a : ((u < 8) ? b : ((u < 12) ? c : d));
  int r = u & 3;
  return (r == 0) ? q.x : ((r == 1) ? q.y : ((r == 2) ? q.z : q.w));
}
__device__ __forceinline__ void set4(float4& a, float4& b, float4& c, float4& d,
                                     int u, float v){
  float4& q = (u < 4) ? a : ((u < 8) ? b : ((u < 12) ? c : d));
  int r = u & 3;
  if (r == 0) q.x = v; else if (r == 1) q.y = v; else if (r == 2) q.z = v; else q.w = v;
}

// ---------------- sequential scan: 1 wave, VALU-only (readlane-dense) -----
template<int BF>
__global__ __launch_bounds__(64, 1) void k_scan(float* ws, float* yout){
  const int* wsi = (const int*)ws;
  if ((wsi[OFF_FLAG] != 0) != (BF != 0)) return;
  const int lane = threadIdx.x;
  const int s = lane < SUBU ? lane : SUBU - 1;
  float m[SUBU];
  #pragma unroll
  for (int k = 0; k < SUBU; ++k) m[k] = ws[OFF_MD + s*SUBU + k];
  const float* cc = ws + OFF_IIR + s*16;
  const float rh0 = cc[0],  kp0 = cc[1],  ay0 = cc[2],  ey0 = cc[3];
  const float rh1 = cc[4],  kp1 = cc[5],  ay1 = cc[6],  ey1 = cc[7];
  const float rh2 = cc[8],  kp2 = cc[9],  ay2 = cc[10], ey2 = cc[11];
  const float cA  = cc[12], cE  = cc[13];
  const float wsub0 = ws[OFF_PAR + SUBU];
  const float vo    = ws[OFF_PAR + SUBU + 1];
  const float* syncol = ws + OFF_SYN + s*TPAD;
  const float TK = 2.8853900817779268f;   // 2*log2(e)

  float yhv[66];
  #pragma unroll
  for (int j = 0; j < 66; ++j) yhv[j] = 0.f;
  float A0 = 0.f, E0 = 0.f, A1 = 0.f, E1 = 0.f, A2 = 0.f, E2 = 0.f;
  float4 u0 = *(const float4*)(syncol + 0);
  float4 u1 = *(const float4*)(syncol + 4);
  float4 u2 = *(const float4*)(syncol + 8);
  float4 u3 = *(const float4*)(syncol + 12);
  float4 n0, n1, n2, n3;
  float xpre = u0.x;                       // c[0] + h[0], h[0]=0

  auto block16 = [&](int tbase, float4& b0, float4& b1, float4& b2, float4& b3,
                     float4& p0, float4& p1, float4& p2, float4& p3){
    const float4* src = (const float4*)(syncol + tbase + 16);
    p0 = src[0]; p1 = src[1]; p2 = src[2]; p3 = src[3];
    float4 ob0, ob1, ob2, ob3;
    #pragma unroll
    for (int u = 0; u < 16; ++u){
      float yprev = yhv[u + 49];           // y[t-1]
      int yb = __float_as_int(yprev);
      // dense prop = M . y[t-1] via readlane broadcast (VALU only)
      float acc0 = fmaf(__int_as_float(__builtin_amdgcn_readlane(yb, 0)),  m[0],  xpre);
      float acc1 = __int_as_float(__builtin_amdgcn_readlane(yb, 1)) * m[1];
      float acc2 = __int_as_float(__builtin_amdgcn_readlane(yb, 2)) * m[2];
      float acc3 = __int_as_float(__builtin_amdgcn_readlane(yb, 3)) * m[3];
      #pragma unroll
      for (int k = 4; k < SUBU; k += 4){
        acc0 = fmaf(__int_as_float(__builtin_amdgcn_readlane(yb, k)),   m[k],   acc0);
        acc1 = fmaf(__int_as_float(__builtin_amdgcn_readlane(yb, k+1)), m[k+1], acc1);
        acc2 = fmaf(__int_as_float(__builtin_amdgcn_readlane(yb, k+2)), m[k+2], acc2);
        acc3 = fmaf(__int_as_float(__builtin_amdgcn_readlane(yb, k+3)), m[k+3], acc3);
      }
      float x  = (acc0 + acc1) + (acc2 + acc3);
      // tanh(x) = 1 - 2/(exp2(TK*x)+1)
      float ex = __builtin_amdgcn_exp2f(TK * x);
      float y  = fmaf(-2.f, __builtin_amdgcn_rcpf(ex + 1.f), 1.f);
      yhv[u + 50] = y;
      // folded IIR history -> h[t+1] (newest tap is y[t-1])
      float A0n = fmaf(rh0, A0, fmaf(kp0, E0, ay0 * yprev));
      E0 = fmaf(rh0, E0, ey0 * yprev); A0 = A0n;
      float A1n = fmaf(rh1, A1, fmaf(kp1, E1, ay1 * yprev));
      E1 = fmaf(rh1, E1, ey1 * yprev); A1 = A1n;
      float yold = yhv[u];                 // y[t-50] correction (slow basis)
      float A2n = fmaf(rh2, A2, fmaf(kp2, E2, fmaf(-cA, yold, ay2 * yprev)));
      E2 = fmaf(rh2, E2, fmaf(-cE, yold, ey2 * yprev)); A2 = A2n;
      float h = (A0 + A1) + A2;
      float cn = (u < 15) ? get4(b0, b1, b2, b3, u + 1) : p0.x;
      xpre = cn + h;
      set4(ob0, ob1, ob2, ob3, u, fmaf(y, wsub0, vo));
    }
    #pragma unroll
    for (int j = 0; j < 50; ++j) yhv[j] = yhv[j + 16];
    if (lane == 0 && tbase + 16 <= T_DATA){
      float4* q = (float4*)(yout + tbase);
      q[0] = ob0; q[1] = ob1; q[2] = ob2; q[3] = ob3;
    }
  };

  #pragma unroll 1
  for (int ib = 0; ib < 628; ++ib){        // 628*32 = 20096 steps
    block16(ib*32,      u0, u1, u2, u3, n0, n1, n2, n3);
    block16(ib*32 + 16, n0, n1, n2, n3, u0, u1, u2, u3);
  }
}

// ---------------- epilogue: f32 Y -> bf16 output (bf16 case only) ---------
__global__ __launch_bounds__(256) void k_out(const float* ws, void* outp){
  const int* wsi = (const int*)ws;
  if (wsi[OFF_FLAG] == 0) return;          // f32: scan wrote d_out directly
  int i = blockIdx.x * 256 + threadIdx.x;
  if (i < T_DATA)
    ((__hip_bfloat16*)outp)[i] = __float2bfloat16(ws[OFF_Y + i]);
}

// --------------------------------------------------------------------------
extern "C" void kernel_launch(void* const* d_in, const int* in_sizes, int n_in,
                              void* d_out, int out_size, void* d_ws, size_t ws_size,
                              hipStream_t stream){
  const void* S_e   = d_in[0];
  const void* S_i   = d_in[1];
  const void* C_den = d_in[2];
  const void* C_e   = d_in[3];
  const void* C_i   = d_in[4];
  const void* W_syn = d_in[5];
  const void* Tau_s = d_in[6];
  const void* D_syn = d_in[7];
  const void* W_hst = d_in[8];
  const void* Tau_h = d_in[9];
  const void* D_hst = d_in[10];
  const void* W_sub = d_in[11];
  const void* V_o   = d_in[12];
  const void* Theta = d_in[13];
  float* ws = (float*)d_ws;
  int* flagp = (int*)(ws + OFF_FLAG);

  k_detect<<<1, 256, 0, stream>>>(S_e, flagp);
  k_prep<<<1, 512, 0, stream>>>(C_den, W_syn, Tau_s, D_syn, W_hst, Tau_h, D_hst,
                                W_sub, V_o, Theta, ws);
  k_gemm<<<5000, 64, 0, stream>>>(S_e, C_e, E_NO, ws + OFF_INE, flagp);
  k_gemm<<<5000, 64, 0, stream>>>(S_i, C_i, I_NO, ws + OFF_INI, flagp);
  dim3 cgrid(79, 20);
  k_conv<<<cgrid, 256, 0, stream>>>(ws);
  k_scan<0><<<1, 64, 0, stream>>>(ws, (float*)d_out);
  k_scan<1><<<1, 64, 0, stream>>>(ws, ws + OFF_Y);
  k_out<<<79, 256, 0, stream>>>(ws, d_out);
}

// Round 4
// 2159.826 us; speedup vs baseline: 1.5194x; 1.5194x over previous
//
#include <hip/hip_runtime.h>
#include <hip/hip_bf16.h>
#include <stdint.h>

#define SUBU 20
#define E_NO 2000
#define I_NO 500
#define T_DATA 20000
#define T_SYNK 200
#define T_HISTK 50
#define SBAS 3
#define HBAS 3
#define TPAD 20096          // 1256 * 16
#define KSTORE 12

// workspace float offsets
#define OFF_SYN  0          // [20][TPAD]  c[s][t] = TK*(syn + theta + rowsum)
#define OFF_INE  401920     // [20][TPAD]
#define OFF_INI  803840     // [20][TPAD]  (reused as Y f32 when bf16 out)
#define OFF_KE   1205760    // [20][200]
#define OFF_KI   1209760    // [20][200]
#define OFF_IIR  1213760    // [20][16] folded IIR consts (A-side TK-scaled)
#define OFF_MW   1214760    // [20][KSTORE]  mwp = -2*TK*m
#define OFF_MIDX 1215000    // [20][KSTORE] ints
#define OFF_PAR  1215240    // TK*(theta+rowsum)[20], wsub0, vo, ksel(int at +23)
#define OFF_FLAG 1215264    // int bf16 flag
#define OFF_Y    OFF_INI

#define TKC 2.8853900817779268f   // 2*log2(e)

__device__ __forceinline__ float bf2f(unsigned short u){
  unsigned v = ((unsigned)u) << 16; float f; __builtin_memcpy(&f, &v, 4); return f;
}
__device__ __forceinline__ float ldany(const void* p, int i, int bf){
  return bf ? bf2f(((const unsigned short*)p)[i]) : ((const float*)p)[i];
}

// ---------------- dtype detection: S_e is exactly {0,1} -------------------
__global__ __launch_bounds__(256) void k_detect(const void* s_e, int* flag){
  __shared__ int found;
  if (threadIdx.x == 0) found = 0;
  __syncthreads();
  const unsigned* w = (const unsigned*)s_e;
  int hit = 0;
  for (int i = threadIdx.x; i < 8192; i += 256){
    unsigned x = w[i];
    if (x == 0x00003F80u || x == 0x3F803F80u) hit = 1;   // bf16 1.0 patterns
  }
  if (hit) atomicOr(&found, 1);
  __syncthreads();
  if (threadIdx.x == 0) *flag = found;
}

// ---------------- precompute: syn kernels, folded IIR, sparse M, params ---
__global__ __launch_bounds__(512) void k_prep(
    const void* Cden, const void* Wsyn, const void* Tausyn, const void* Dsyn,
    const void* Whist, const void* Tauhist, const void* Dhist,
    const void* Wsub, const void* Vo, const void* Theta, float* ws){
  int* wsi = (int*)ws;
  const int bf = wsi[OFF_FLAG];
  const int tx = threadIdx.x;
  __shared__ int mx;
  if (tx == 0) mx = 0;
  __syncthreads();
  // synaptic kernels ke/ki [20][200]
  for (int idx = tx; idx < SUBU * T_SYNK; idx += 512){
    int s = idx / T_SYNK, t = idx % T_SYNK;
    for (int c = 0; c < 2; ++c){
      float delta = __expf(ldany(Dsyn, s*2 + c, bf));
      float acc = 0.f;
      for (int b = 0; b < SBAS; ++b){
        float tau = __expf(ldany(Tausyn, b*2 + c, bf));
        float w   = ldany(Wsyn, (s*SBAS + b)*2 + c, bf);
        float tt  = fmaxf((float)t - delta, 0.f) / tau;
        acc += w * tt * __expf(-tt);
      }
      ws[(c == 0 ? OFF_KE : OFF_KI) + s*T_SYNK + t] = acc;
    }
  }
  // folded per-lane IIR constants; A-side carries TK*w
  if (tx < SUBU * HBAS){
    int s = tx / HBAS, b = tx % HBAS;
    float tau = __expf(ldany(Tauhist, b, bf));
    float w   = TKC * ldany(Whist, s*HBAS + b, bf);   // TK fold
    float dl  = ldany(Dhist, s, bf);
    float rho = __expf(-1.f / tau);
    float e1  = __expf(-(1.f - dl) / tau);
    float g1  = ((1.f - dl) / tau) * e1;
    float kap = rho / tau;
    float* c = ws + OFF_IIR + s*16 + b*4;
    c[0] = rho;          // decay
    c[1] = w * kap;      // E -> A  (TK-scaled)
    c[2] = w * g1;       // y_new into A (TK-scaled)
    c[3] = e1;           // y_new into E (unscaled)
    if (b == 2){         // slow basis window-correction taps
      float e49 = __expf(-(49.f - dl) / tau);
      float g49 = ((49.f - dl) / tau) * e49;
      ws[OFF_IIR + s*16 + 12] = w * (rho*g49 + kap*e49);  // TK-scaled
      ws[OFF_IIR + s*16 + 13] = rho * e49;                // E-side, unscaled
    }
  }
  // sparse gather weights: mwp = -2*TK*C_den*W_sub ; rowsum fold into PAR
  if (tx < SUBU){
    int s = tx, cnt = 0;
    float rowsum = 0.f;
    for (int sp = 0; sp < SUBU; ++sp){
      float c = ldany(Cden, s*SUBU + sp, bf);
      if (c != 0.f && cnt < KSTORE){
        float m = c * ldany(Wsub, sp, bf);
        rowsum += m;
        ws[OFF_MW + s*KSTORE + cnt]  = -2.f * TKC * m;
        wsi[OFF_MIDX + s*KSTORE + cnt] = sp;
        ++cnt;
      }
    }
    for (int k = cnt; k < KSTORE; ++k){
      ws[OFF_MW + s*KSTORE + k] = 0.f; wsi[OFF_MIDX + s*KSTORE + k] = 0;
    }
    atomicMax(&mx, cnt);
    ws[OFF_PAR + s] = TKC * (ldany(Theta, s, bf) + rowsum);
  }
  __syncthreads();
  if (tx == 0){
    ws[OFF_PAR + SUBU]     = ldany(Wsub, 0, bf);
    ws[OFF_PAR + SUBU + 1] = ldany(Vo, 0, bf);
    wsi[OFF_PAR + 23] = (mx <= 6) ? 6 : 12;
  }
}

// ---------------- skinny GEMM: in_T[s][t] = sum_e S[t][e]*C[s][e] ---------
template<int BF>
__device__ __forceinline__ void gemm_impl(const void* S, const void* C, int W,
                                          float* dst, int t0, int lane){
  float acc[4][SUBU];
  #pragma unroll
  for (int r = 0; r < 4; ++r)
    #pragma unroll
    for (int s = 0; s < SUBU; ++s) acc[r][s] = 0.f;
  for (int e = lane; e < W; e += 64){
    float s0 = ldany(S, (t0+0)*W + e, BF);
    float s1 = ldany(S, (t0+1)*W + e, BF);
    float s2 = ldany(S, (t0+2)*W + e, BF);
    float s3 = ldany(S, (t0+3)*W + e, BF);
    #pragma unroll
    for (int s = 0; s < SUBU; ++s){
      float c = ldany(C, s*W + e, BF);
      acc[0][s] = fmaf(s0, c, acc[0][s]);
      acc[1][s] = fmaf(s1, c, acc[1][s]);
      acc[2][s] = fmaf(s2, c, acc[2][s]);
      acc[3][s] = fmaf(s3, c, acc[3][s]);
    }
  }
  #pragma unroll
  for (int r = 0; r < 4; ++r){
    #pragma unroll
    for (int s = 0; s < SUBU; ++s){
      float v = acc[r][s];
      #pragma unroll
      for (int m = 32; m >= 1; m >>= 1) v += __shfl_xor(v, m, 64);
      if (lane == 0) dst[s*TPAD + t0 + r] = v;
    }
  }
}

__global__ __launch_bounds__(64) void k_gemm(const void* S, const void* C, int W,
                                             float* dst, const int* flagp){
  int t0 = blockIdx.x * 4, lane = threadIdx.x;
  if (*flagp) gemm_impl<1>(S, C, W, dst, t0, lane);
  else        gemm_impl<0>(S, C, W, dst, t0, lane);
}

// ---------------- causal conv (+theta/rowsum fold, TK scale): c[s][t] -----
__global__ __launch_bounds__(256) void k_conv(float* ws){
  const int s  = blockIdx.y;
  const int t0 = blockIdx.x * 256;
  const float* ine = ws + OFF_INE + s*TPAD;
  const float* ini = ws + OFF_INI + s*TPAD;
  __shared__ float eL[455], iL[455], keL[T_SYNK], kiL[T_SYNK];
  for (int j = threadIdx.x; j < 455; j += 256){
    int t = t0 - 199 + j;
    bool ok = (t >= 0 && t < TPAD);
    eL[j] = ok ? ine[t] : 0.f;
    iL[j] = ok ? ini[t] : 0.f;
  }
  for (int j = threadIdx.x; j < T_SYNK; j += 256){
    keL[j] = ws[OFF_KE + s*T_SYNK + j];
    kiL[j] = ws[OFF_KI + s*T_SYNK + j];
  }
  __syncthreads();
  int t = t0 + threadIdx.x;
  if (t < TPAD){
    float a0 = 0.f, a1 = 0.f;
    #pragma unroll 4
    for (int k = 0; k < T_SYNK; ++k){
      a0 = fmaf(keL[k], eL[threadIdx.x + 199 - k], a0);
      a1 = fmaf(kiL[k], iL[threadIdx.x + 199 - k], a1);
    }
    ws[OFF_SYN + s*TPAD + t] = fmaf(TKC, a0 + a1, ws[OFF_PAR + s]);
  }
}

// ---------------- static float4 component helpers -------------------------
__device__ __forceinline__ float get4(const float4& a, const float4& b,
                                      const float4& c, const float4& d, int u){
  const float4& q = (u < 4) ? a : ((u < 8) ? b : ((u < 12) ? c : d));
  int r = u & 3;
  return (r == 0) ? q.x : ((r == 1) ? q.y : ((r == 2) ? q.z : q.w));
}
__device__ __forceinline__ void set4(float4& a, float4& b, float4& c, float4& d,
                                     int u, float v){
  float4& q = (u < 4) ? a : ((u < 8) ? b : ((u < 12) ? c : d));
  int r = u & 3;
  if (r == 0) q.x = v; else if (r == 1) q.y = v; else if (r == 2) q.z = v; else q.w = v;
}

// ---------------- sequential scan: 1 wave, r-gather bpermute --------------
template<int KM, int BF>
__global__ __launch_bounds__(64, 1) void k_scan(float* ws, float* yout){
  const int* wsi = (const int*)ws;
  if ((wsi[OFF_FLAG] != 0) != (BF != 0)) return;
  if (wsi[OFF_PAR + 23] != KM) return;
  const int lane = threadIdx.x;
  const int s = lane < SUBU ? lane : SUBU - 1;
  float mwp[KM]; int mad[KM];
  #pragma unroll
  for (int k = 0; k < KM; ++k){
    mwp[k] = ws[OFF_MW + s*KSTORE + k];
    mad[k] = wsi[OFF_MIDX + s*KSTORE + k] * 4;
  }
  const float* cc = ws + OFF_IIR + s*16;
  const float rh0 = cc[0],  kp0 = cc[1],  ay0 = cc[2],  ey0 = cc[3];
  const float rh1 = cc[4],  kp1 = cc[5],  ay1 = cc[6],  ey1 = cc[7];
  const float rh2 = cc[8],  kp2 = cc[9],  ay2 = cc[10], ey2 = cc[11];
  const float cA  = cc[12], cE  = cc[13];
  const float wsub0 = ws[OFF_PAR + SUBU];
  const float vo    = ws[OFF_PAR + SUBU + 1];
  const float* syncol = ws + OFF_SYN + s*TPAD;

  float yhv[66];
  #pragma unroll
  for (int j = 0; j < 66; ++j) yhv[j] = 0.f;
  float A0 = 0.f, E0 = 0.f, A1 = 0.f, E1 = 0.f, A2 = 0.f, E2 = 0.f;
  float pb[KM];
  #pragma unroll
  for (int k = 0; k < KM; ++k) pb[k] = 0.5f;      // r for y=0
  float4 u0 = *(const float4*)(syncol + 0);
  float4 u1 = *(const float4*)(syncol + 4);
  float4 u2 = *(const float4*)(syncol + 8);
  float4 u3 = *(const float4*)(syncol + 12);
  float4 n0, n1, n2, n3;
  float xpre = u0.x;                               // X[0] partial, h=0

  auto block16 = [&](int tbase, float4& b0, float4& b1, float4& b2, float4& b3,
                     float4& p0, float4& p1, float4& p2, float4& p3){
    const float4* src = (const float4*)(syncol + tbase + 16);
    p0 = src[0]; p1 = src[1]; p2 = src[2]; p3 = src[3];
    float4 ob0, ob1, ob2, ob3;
    #pragma unroll
    for (int u = 0; u < 16; ++u){
      // X[t] = xpre + sum_k mwp[k]*r_gathered[k]   (mwp = -2*TK*m)
      float acc0 = fmaf(mwp[0], pb[0], xpre);
      float acc1 = mwp[1] * pb[1];
      #pragma unroll
      for (int k = 2; k + 1 < KM; k += 2){
        acc0 = fmaf(mwp[k],   pb[k],   acc0);
        acc1 = fmaf(mwp[k+1], pb[k+1], acc1);
      }
      float X  = acc0 + acc1;
      float ex = __builtin_amdgcn_exp2f(X);
      float r  = __builtin_amdgcn_rcpf(ex + 1.f);
      // issue next step's gathers ASAP; everything below runs in DS shadow
      int rb = __float_as_int(r);
      #pragma unroll
      for (int k = 0; k < KM; ++k)
        pb[k] = __int_as_float(__builtin_amdgcn_ds_bpermute(mad[k], rb));
      float y = fmaf(-2.f, r, 1.f);
      float yprev = yhv[u + 49];                   // y[t-1]
      float yold  = yhv[u];                        // y[t-50]
      // folded IIR -> h[t+1] (TK-scaled via A-side weights)
      float A0n = fmaf(rh0, A0, fmaf(kp0, E0, ay0 * yprev));
      E0 = fmaf(rh0, E0, ey0 * yprev); A0 = A0n;
      float A1n = fmaf(rh1, A1, fmaf(kp1, E1, ay1 * yprev));
      E1 = fmaf(rh1, E1, ey1 * yprev); A1 = A1n;
      float A2n = fmaf(rh2, A2, fmaf(kp2, E2, fmaf(-cA, yold, ay2 * yprev)));
      E2 = fmaf(rh2, E2, fmaf(-cE, yold, ey2 * yprev)); A2 = A2n;
      float h = (A0 + A1) + A2;
      float cn = (u < 15) ? get4(b0, b1, b2, b3, u + 1) : p0.x;
      xpre = cn + h;
      yhv[u + 50] = y;
      set4(ob0, ob1, ob2, ob3, u, fmaf(y, wsub0, vo));
    }
    #pragma unroll
    for (int j = 0; j < 50; ++j) yhv[j] = yhv[j + 16];
    if (lane == 0 && tbase + 16 <= T_DATA){
      float4* q = (float4*)(yout + tbase);
      q[0] = ob0; q[1] = ob1; q[2] = ob2; q[3] = ob3;
    }
  };

  #pragma unroll 1
  for (int ib = 0; ib < 628; ++ib){                // 628*32 = 20096 steps
    block16(ib*32,      u0, u1, u2, u3, n0, n1, n2, n3);
    block16(ib*32 + 16, n0, n1, n2, n3, u0, u1, u2, u3);
  }
}

// ---------------- epilogue: f32 Y -> bf16 output (bf16 case only) ---------
__global__ __launch_bounds__(256) void k_out(const float* ws, void* outp){
  const int* wsi = (const int*)ws;
  if (wsi[OFF_FLAG] == 0) return;
  int i = blockIdx.x * 256 + threadIdx.x;
  if (i < T_DATA)
    ((__hip_bfloat16*)outp)[i] = __float2bfloat16(ws[OFF_Y + i]);
}

// --------------------------------------------------------------------------
extern "C" void kernel_launch(void* const* d_in, const int* in_sizes, int n_in,
                              void* d_out, int out_size, void* d_ws, size_t ws_size,
                              hipStream_t stream){
  const void* S_e   = d_in[0];
  const void* S_i   = d_in[1];
  const void* C_den = d_in[2];
  const void* C_e   = d_in[3];
  const void* C_i   = d_in[4];
  const void* W_syn = d_in[5];
  const void* Tau_s = d_in[6];
  const void* D_syn = d_in[7];
  const void* W_hst = d_in[8];
  const void* Tau_h = d_in[9];
  const void* D_hst = d_in[10];
  const void* W_sub = d_in[11];
  const void* V_o   = d_in[12];
  const void* Theta = d_in[13];
  float* ws = (float*)d_ws;
  int* flagp = (int*)(ws + OFF_FLAG);

  k_detect<<<1, 256, 0, stream>>>(S_e, flagp);
  k_prep<<<1, 512, 0, stream>>>(C_den, W_syn, Tau_s, D_syn, W_hst, Tau_h, D_hst,
                                W_sub, V_o, Theta, ws);
  k_gemm<<<5000, 64, 0, stream>>>(S_e, C_e, E_NO, ws + OFF_INE, flagp);
  k_gemm<<<5000, 64, 0, stream>>>(S_i, C_i, I_NO, ws + OFF_INI, flagp);
  dim3 cgrid(79, 20);
  k_conv<<<cgrid, 256, 0, stream>>>(ws);
  k_scan<6, 0><<<1, 64, 0, stream>>>(ws, (float*)d_out);
  k_scan<6, 1><<<1, 64, 0, stream>>>(ws, ws + OFF_Y);
  k_scan<12, 0><<<1, 64, 0, stream>>>(ws, (float*)d_out);
  k_scan<12, 1><<<1, 64, 0, stream>>>(ws, ws + OFF_Y);
  k_out<<<79, 256, 0, stream>>>(ws, d_out);
}